// Round 2
// 104.559 us; speedup vs baseline: 1.0305x; 1.0305x over previous
//
#include <hip/hip_runtime.h>

// MultiAgentLinearLayer via bf16 MFMA, round 4 (resubmit — R1 bench was a
// broker timeout, no data): cvt_pk packing + nfrag cut + primed W prefetch +
// XCD-colocated n-tiles.
// out[b,o] = sum_k W[agent[b],o,k]*x[b,k] + bias[agent[b],o]
// B=2048, I=O=512, 64 agents, fp32 in/out. Threshold 5.97e-2 permits bf16.
//
// Structure (unchanged skeleton from round 3, proven correct):
//  - block = 1024 threads = 16 waves; 256 blocks (1/CU), one (agent, 128-col
//    n-tile) each. Waves 0..7: n-subtile w8*16, K-half [0,256); waves 8..15:
//    K-half [256,512). Partials reduced via padded LDS Rs (stride 17).
//  - W streamed global->registers, 3-deep float4x2 prefetch PRIMED AT
//    KERNEL TOP so HBM latency overlaps compaction + X staging.
//  - X staged once to LDS as bf16 (stride 520, conflict-free b128 reads).
// Round-4 deltas:
//  - fp32->bf16 via scalar __bf16 casts (compiler emits v_cvt_pk_bf16_f32,
//    ~1 op/pair vs ~11 for manual bit-RTN; same RNE rounding -> same absmax).
//  - nfrag = ceil(mcount/16): skip A-frag ds_reads/MFMAs/Rs/epilogue beyond
//    live rows (count~32 -> ~half the K-phase LDS+MFMA work). Dead X rows
//    are neither loaded nor zeroed (their acc entries are never stored).
//  - block-ID swizzle: an agent's 4 n-tile blocks share bid%8 -> same XCD
//    (round-robin dispatch) -> X rows hit that XCD's L2 instead of HBM x4.
//  - one fewer barrier per chunk (staging never touches Rs; park/epilogue
//    never touch Xs -> 2 barriers/chunk suffice).

constexpr int BATCH  = 2048;
constexpr int NAGENT = 64;
constexpr int IN_F   = 512;
constexpr int OUT_F  = 512;

constexpr int BN  = 128;        // block n-tile
constexpr int MCH = 64;         // m rows per chunk (count<=64 in practice)
constexpr int XS  = IN_F + 8;   // X LDS stride in bf16 elems (520)

typedef __attribute__((ext_vector_type(8))) short short8;     // bf16 A/B frag
typedef __attribute__((ext_vector_type(4))) float f32x4;      // fp32 C/D frag
typedef __attribute__((ext_vector_type(4))) unsigned int u32x4;
typedef __bf16 bf16x2 __attribute__((ext_vector_type(2)));

__device__ inline unsigned pk_bf(float lo, float hi) {
  // compiler pairs adjacent casts into v_cvt_pk_bf16_f32 (RNE, same as the
  // old manual +0x7FFF+lsb rounding)
  bf16x2 v;
  v[0] = (__bf16)lo;
  v[1] = (__bf16)hi;
  return __builtin_bit_cast(unsigned, v);
}

__global__ __launch_bounds__(1024, 4) void agent_linear_mfma4(
    const int*   __restrict__ which,
    const float* __restrict__ x,
    const float* __restrict__ weight,
    const float* __restrict__ bias,
    float*       __restrict__ out) {
  const int tid   = threadIdx.x;
  const int lane  = tid & 63;
  const int wid   = tid >> 6;        // 0..15
  const int w8    = wid & 7;         // n-wave within BN
  const int kh    = wid >> 3;        // k-half: 0 or 1

  // bid = (a&7) + 8*n + 32*(a>>3): agent a's 4 n-tiles all share bid%8
  const int bid   = blockIdx.x;      // 0..255
  const int agent = (bid & 7) | ((bid >> 5) << 3);
  const int obase = ((bid >> 3) & 3) * BN;

  __shared__ int rowlist_s[BATCH];                       // 8 KB
  __shared__ int wsum_s[16];
  __shared__ __align__(16) unsigned short Xs[MCH * XS];  // 65 KB bf16
  __shared__ float Rs[8][MCH][17];                       // 34 KB, k-half partials

  const int nl = lane & 15;      // n within frag / m within A-frag
  const int kq = lane >> 4;      // k-quad 0..3

  const float* wp = weight + ((size_t)(agent * OUT_F + obase + w8 * 16 + nl)) * IN_F
                  + kh * 256 + kq * 8;

  // ---- prime 3-deep W prefetch NOW: latency hides under compaction+staging ----
  float4 pa[3], pb[3];
#pragma unroll
  for (int j = 0; j < 3; ++j) {
    pa[j] = *(const float4*)(wp + j * 32);
    pb[j] = *(const float4*)(wp + j * 32 + 4);
  }

  const float bv = bias[agent * OUT_F + obase + w8 * 16 + nl];

  // ---- stable compaction: rows with which[i]==agent, ascending ----
  int2 v = ((const int2*)which)[tid];                    // 2 vals/thread
  int lc = (v.x == agent) + (v.y == agent);
  int s = lc;
#pragma unroll
  for (int off = 1; off < 64; off <<= 1) {
    int t = __shfl_up(s, off);
    if (lane >= off) s += t;
  }
  if (lane == 63) wsum_s[wid] = s;
  __syncthreads();
  int base = 0, count = 0;
#pragma unroll
  for (int w = 0; w < 16; ++w) {
    int ws = wsum_s[w];
    if (w < wid) base += ws;
    count += ws;
  }
  {
    int pos = base + s - lc;
    if (v.x == agent) rowlist_s[pos++] = 2 * tid;
    if (v.y == agent) rowlist_s[pos]   = 2 * tid + 1;
  }
  __syncthreads();   // rowlist ready

  for (int m0 = 0; m0 < count; m0 += MCH) {
    const int mcount = min(MCH, count - m0);
    const int nfrag  = (mcount + 15) >> 4;   // live 16-row A-frags (1..4)

    // ---- stage X chunk: only live rows; dead rows never stored from ----
#pragma unroll
    for (int t = 0; t < 8; ++t) {
      int idx = t * 1024 + tid;
      int r   = idx >> 7;          // 0..63 (wave-uniform per t)
      int c4  = idx & 127;         // float4 column
      if (r < mcount) {
        float4 xv = *(const float4*)(x + (size_t)rowlist_s[m0 + r] * IN_F + c4 * 4);
        uint2 w2;
        w2.x = pk_bf(xv.x, xv.y);
        w2.y = pk_bf(xv.z, xv.w);
        *(uint2*)&Xs[r * XS + c4 * 4] = w2;
      }
    }
    __syncthreads();   // Xs ready

    // ---- barrier-free K-loop over this wave's 256-k half ----
    f32x4 acc[4] = {{0.f,0.f,0.f,0.f},{0.f,0.f,0.f,0.f},
                    {0.f,0.f,0.f,0.f},{0.f,0.f,0.f,0.f}};
    const int kbase = kh * 256;
#pragma unroll
    for (int k = 0; k < 8; ++k) {
      float4 c0 = pa[k % 3], c1 = pb[k % 3];
      if (k + 3 < 8) {
        pa[k % 3] = *(const float4*)(wp + (k + 3) * 32);
        pb[k % 3] = *(const float4*)(wp + (k + 3) * 32 + 4);
      }
      u32x4 q;
      q[0] = pk_bf(c0.x, c0.y); q[1] = pk_bf(c0.z, c0.w);
      q[2] = pk_bf(c1.x, c1.y); q[3] = pk_bf(c1.z, c1.w);
      short8 bfr = __builtin_bit_cast(short8, q);
#pragma unroll
      for (int i = 0; i < 4; ++i) {
        if (i < nfrag) {   // wave-uniform: skip dead-row frags entirely
          short8 af = *(const short8*)&Xs[(i * 16 + nl) * XS + kbase + k * 32 + kq * 8];
          acc[i] = __builtin_amdgcn_mfma_f32_16x16x32_bf16(af, bfr, acc[i], 0, 0, 0);
        }
      }
    }

    // ---- cross-k-half reduction: upper waves park partials in LDS ----
    if (kh == 1) {
#pragma unroll
      for (int i = 0; i < 4; ++i)
        if (i < nfrag)
#pragma unroll
          for (int r = 0; r < 4; ++r)
            Rs[w8][i * 16 + kq * 4 + r][nl] = acc[i][r];
    }
    __syncthreads();   // Rs ready; all Xs reads of this chunk also complete

    // ---- epilogue by lower waves: D row=(lane>>4)*4+reg, col=lane&15 ----
    if (kh == 0) {
#pragma unroll
      for (int i = 0; i < 4; ++i) {
        if (i < nfrag) {
#pragma unroll
          for (int r = 0; r < 4; ++r) {
            int m = i * 16 + kq * 4 + r;
            if (m < mcount) {
              out[(size_t)rowlist_s[m0 + m] * OUT_F + obase + w8 * 16 + nl] =
                  acc[i][r] + Rs[w8][m][nl] + bv;
            }
          }
        }
      }
    }

    if (m0 + MCH < count) {   // re-prime for the (rare) next chunk; L2-hot
#pragma unroll
      for (int j = 0; j < 3; ++j) {
        pa[j] = *(const float4*)(wp + j * 32);
        pb[j] = *(const float4*)(wp + j * 32 + 4);
      }
    }
  }
}

extern "C" void kernel_launch(void* const* d_in, const int* in_sizes, int n_in,
                              void* d_out, int out_size, void* d_ws, size_t ws_size,
                              hipStream_t stream) {
  const int*   which = (const int*)d_in[0];
  const float* x     = (const float*)d_in[1];
  const float* w     = (const float*)d_in[2];
  const float* b     = (const float*)d_in[3];
  float*       out   = (float*)d_out;

  dim3 grid(OUT_F / BN * NAGENT);   // 256 blocks, 1 per CU (swizzled decode)
  agent_linear_mfma4<<<grid, dim3(1024), 0, stream>>>(which, x, w, b, out);
}